// Round 1
// baseline (138.546 us; speedup 1.0000x reference)
//
#include <hip/hip_runtime.h>
#include <math.h>

#define EMBED_DIM 64
#define MAX_NEIGH 50

// broadcast lane `lane`'s value of v to all lanes via v_readlane (SGPR path,
// stays off the LDS pipe; `lane` is wave-uniform)
__device__ __forceinline__ float bcastf(float v, int lane) {
    return __int_as_float(__builtin_amdgcn_readlane(__float_as_int(v), lane));
}

__global__ __launch_bounds__(512) void graphrec_agg_kernel(
    const float* __restrict__ u_table,
    const float* __restrict__ i_table,
    const float* __restrict__ W1, const float* __restrict__ b1,
    const float* __restrict__ W2, const float* __restrict__ b2,
    const float* __restrict__ W3, const float* __restrict__ b3,
    const int* __restrict__ nodes,
    const int* __restrict__ neighbors,
    const int* __restrict__ lengths,
    float* __restrict__ out)
{
    // weights staged once per block, shared by 8 waves (8 batch elements)
    __shared__ float W1s[128 * 64];   // 32 KB
    __shared__ float W2s[64 * 64];    // 16 KB
    __shared__ float W3s[64];
    __shared__ float b1s[64];
    __shared__ float b2s[64];

    const int tid = threadIdx.x;
    for (int i = tid; i < 128 * 64; i += 512) W1s[i] = W1[i];
    for (int i = tid; i < 64 * 64;  i += 512) W2s[i] = W2[i];
    if (tid < 64) { W3s[tid] = W3[tid]; b1s[tid] = b1[tid]; b2s[tid] = b2[tid]; }
    __syncthreads();

    const int wave = tid >> 6;
    const int j    = tid & 63;          // lane j owns output dim j
    const int b    = blockIdx.x * 8 + wave;   // grid=512 * 8 waves = 4096

    const int   node = nodes[b];
    const int   len  = lengths[b];      // in [1, 50]
    const float b3v  = b3[0];
    const float xu   = u_table[node * EMBED_DIM + j];
    const float w3j  = W3s[j];

    // node-half of layer 1 is identical for every neighbor of b: hoist it.
    // hnode[j] = b1[j] + sum_k xu[k] * W1[64+k][j]
    float hnode = b1s[j];
    #pragma unroll 16
    for (int k = 0; k < 64; ++k) {
        hnode = fmaf(bcastf(xu, k), W1s[(64 + k) * 64 + j], hnode);
    }

    // online softmax accumulation (flash-style): keeps neighbor embeddings
    // register-resident, no second gather pass.
    float m = -INFINITY, ssum = 0.f, acc = 0.f;
    const int ngroups = (len + 3) >> 2;
    for (int g = 0; g < ngroups; ++g) {
        int   nb[4];
        float xn[4];
        #pragma unroll
        for (int u = 0; u < 4; ++u) {
            int l = g * 4 + u;
            if (l > MAX_NEIGH - 1) l = MAX_NEIGH - 1;   // clamp gather; masked below
            nb[u] = neighbors[b * MAX_NEIGH + l];
        }
        #pragma unroll
        for (int u = 0; u < 4; ++u) xn[u] = i_table[nb[u] * EMBED_DIM + j];

        // layer 1 (neighbor half): a_u[j] = hnode[j] + sum_k xn_u[k]*W1[k][j]
        float a0 = hnode, a1 = hnode, a2 = hnode, a3 = hnode;
        #pragma unroll 16
        for (int k = 0; k < 64; ++k) {
            const float wk = W1s[k * 64 + j];     // conflict-free: lane j -> bank j%32
            a0 = fmaf(bcastf(xn[0], k), wk, a0);
            a1 = fmaf(bcastf(xn[1], k), wk, a1);
            a2 = fmaf(bcastf(xn[2], k), wk, a2);
            a3 = fmaf(bcastf(xn[3], k), wk, a3);
        }
        a0 = fmaxf(a0, 0.f); a1 = fmaxf(a1, 0.f); a2 = fmaxf(a2, 0.f); a3 = fmaxf(a3, 0.f);

        // layer 2: c_u[j] = b2[j] + sum_k a_u[k]*W2[k][j]
        float c0 = b2s[j], c1 = b2s[j], c2 = b2s[j], c3 = b2s[j];
        #pragma unroll 16
        for (int k = 0; k < 64; ++k) {
            const float wk = W2s[k * 64 + j];
            c0 = fmaf(bcastf(a0, k), wk, c0);
            c1 = fmaf(bcastf(a1, k), wk, c1);
            c2 = fmaf(bcastf(a2, k), wk, c2);
            c3 = fmaf(bcastf(a3, k), wk, c3);
        }
        // layer 3: logit_u = sum_j relu(c_u[j])*W3[j] + b3  (butterfly reduce)
        c0 = fmaxf(c0, 0.f) * w3j;
        c1 = fmaxf(c1, 0.f) * w3j;
        c2 = fmaxf(c2, 0.f) * w3j;
        c3 = fmaxf(c3, 0.f) * w3j;
        #pragma unroll
        for (int off = 32; off > 0; off >>= 1) {
            c0 += __shfl_xor(c0, off);
            c1 += __shfl_xor(c1, off);
            c2 += __shfl_xor(c2, off);
            c3 += __shfl_xor(c3, off);
        }
        const float p0 = c0 + b3v, p1 = c1 + b3v, p2 = c2 + b3v, p3 = c3 + b3v;

        const int rem = len - g * 4;
        const int nv  = rem < 4 ? rem : 4;    // valid neighbors in this group (wave-uniform)
        float gm = p0;
        if (nv > 1) gm = fmaxf(gm, p1);
        if (nv > 2) gm = fmaxf(gm, p2);
        if (nv > 3) gm = fmaxf(gm, p3);
        const float newm = fmaxf(m, gm);
        const float sc = __expf(m - newm);    // m=-inf on first group -> sc=0
        ssum *= sc; acc *= sc;
        { const float e0 = __expf(p0 - newm); ssum += e0; acc = fmaf(e0, xn[0], acc); }
        if (nv > 1) { const float e1 = __expf(p1 - newm); ssum += e1; acc = fmaf(e1, xn[1], acc); }
        if (nv > 2) { const float e2 = __expf(p2 - newm); ssum += e2; acc = fmaf(e2, xn[2], acc); }
        if (nv > 3) { const float e3 = __expf(p3 - newm); ssum += e3; acc = fmaf(e3, xn[3], acc); }
        m = newm;
    }

    out[b * EMBED_DIM + j] = acc / ssum;
}

extern "C" void kernel_launch(void* const* d_in, const int* in_sizes, int n_in,
                              void* d_out, int out_size, void* d_ws, size_t ws_size,
                              hipStream_t stream) {
    const float* u_table  = (const float*)d_in[0];
    const float* i_table  = (const float*)d_in[1];
    const float* W1       = (const float*)d_in[2];
    const float* b1       = (const float*)d_in[3];
    const float* W2       = (const float*)d_in[4];
    const float* b2       = (const float*)d_in[5];
    const float* W3       = (const float*)d_in[6];
    const float* b3       = (const float*)d_in[7];
    const int*   nodes    = (const int*)d_in[8];
    const int*   neighbors= (const int*)d_in[9];
    const int*   lengths  = (const int*)d_in[10];
    float* out = (float*)d_out;

    graphrec_agg_kernel<<<dim3(512), dim3(512), 0, stream>>>(
        u_table, i_table, W1, b1, W2, b2, W3, b3, nodes, neighbors, lengths, out);
}

// Round 2
// 35.132 us; speedup vs baseline: 3.9435x; 3.9435x over previous
//
#include <hip/hip_runtime.h>
#include <math.h>

#define NB    4096
#define LMAX  50
#define BPB   8      // batch elements per block

typedef short bf16x8 __attribute__((ext_vector_type(8)));
typedef float f32x4  __attribute__((ext_vector_type(4)));

// f32 -> bf16 (RNE), returned as raw bits in a short
__device__ __forceinline__ short f2bf(float f) {
    union { float f; unsigned u; } v; v.f = f;
    unsigned r = v.u + 0x7FFFu + ((v.u >> 16) & 1u);
    return (short)(r >> 16);
}

// load 8 consecutive f32 (32B-aligned) and convert to a bf16x8 fragment
__device__ __forceinline__ bf16x8 cvt8(const float* __restrict__ p) {
    const float4* q = (const float4*)p;
    float4 x = q[0], y = q[1];
    bf16x8 r;
    r[0] = f2bf(x.x); r[1] = f2bf(x.y); r[2] = f2bf(x.z); r[3] = f2bf(x.w);
    r[4] = f2bf(y.x); r[5] = f2bf(y.y); r[6] = f2bf(y.z); r[7] = f2bf(y.w);
    return r;
}

// 4 waves per block; each wave owns one 16-row m-tile of the current batch
// element -> per-b cost is ~constant regardless of len (ragged imbalance gone).
__global__ __launch_bounds__(256) void graphrec_mfma_kernel(
    const float* __restrict__ u_table,
    const float* __restrict__ i_table,
    const float* __restrict__ W1, const float* __restrict__ b1,
    const float* __restrict__ W2, const float* __restrict__ b2,
    const float* __restrict__ W3, const float* __restrict__ b3,
    const int* __restrict__ nodes,
    const int* __restrict__ neighbors,
    const int* __restrict__ lengths,
    float* __restrict__ out)
{
    // per-wave H1 transpose buffer: 16 rows x 72 bf16 (stride 72 shorts = 144B
    // -> b128 reads are 16B-aligned; bank base 4*((l15+g)%8) = even 8-way spread)
    __shared__ __attribute__((aligned(16))) unsigned short Hs[4][16 * 72];
    __shared__ float Ls[64];       // logits for one batch element
    __shared__ float Os[4][64];    // per-wave weighted-sum partials

    const int tid  = threadIdx.x;
    const int w    = tid >> 6;     // wave 0..3
    const int lane = tid & 63;
    const int l15  = lane & 15;
    const int g    = lane >> 4;

    // ---- weight fragments in VGPRs, loaded once per block (L2-resident) ----
    // B-frag layout: lane holds B[k][n], n = nt*16 + l15, k = ks*32 + g*8 + i
    bf16x8 w1f[4][4];   // K=128: ks 0..1 neighbor half, ks 2..3 node half
    #pragma unroll
    for (int ks = 0; ks < 4; ++ks)
        #pragma unroll
        for (int nt = 0; nt < 4; ++nt) {
            bf16x8 f;
            #pragma unroll
            for (int i = 0; i < 8; ++i)
                f[i] = f2bf(W1[(ks * 32 + g * 8 + i) * 64 + nt * 16 + l15]);
            w1f[ks][nt] = f;
        }
    bf16x8 w2f[2][4];
    #pragma unroll
    for (int ks = 0; ks < 2; ++ks)
        #pragma unroll
        for (int nt = 0; nt < 4; ++nt) {
            bf16x8 f;
            #pragma unroll
            for (int i = 0; i < 8; ++i)
                f[i] = f2bf(W2[(ks * 32 + g * 8 + i) * 64 + nt * 16 + l15]);
            w2f[ks][nt] = f;
        }
    float b1v[4], b2v[4], w3v[4];
    #pragma unroll
    for (int nt = 0; nt < 4; ++nt) {
        b1v[nt] = b1[nt * 16 + l15];
        b2v[nt] = b2[nt * 16 + l15];
        w3v[nt] = W3[nt * 16 + l15];
    }
    // b3 shifts all logits equally -> softmax-invariant, skip it.

    for (int u = 0; u < BPB; ++u) {
        const int b    = blockIdx.x * BPB + u;
        const int len  = lengths[b];              // in [1, 50]
        const int mt   = (len + 15) >> 4;         // active m-tiles (1..4)
        const int node = nodes[b];
        const bool active = (w < mt);

        // node-embedding A-fragments (rows 64..127 of the concat are the same
        // xu for every neighbor row -> frag is independent of l15)
        bf16x8 axu0 = cvt8(u_table + node * 64 +      g * 8);
        bf16x8 axu1 = cvt8(u_table + node * 64 + 32 + g * 8);

        // this wave's tile rows: r = w*16 + l15
        const int  r    = w * 16 + l15;
        const bool vrow = active && (r < len);
        int nbr = 0;
        if (vrow) nbr = neighbors[b * LMAX + r];

        if (active) {
            // gather A-fragments of X (zero rows beyond len)
            bf16x8 a0 = {0,0,0,0,0,0,0,0}, a1 = {0,0,0,0,0,0,0,0};
            if (vrow) {
                a0 = cvt8(i_table + nbr * 64 +      g * 8);
                a1 = cvt8(i_table + nbr * 64 + 32 + g * 8);
            }

            // ---- layer 1: H1 = relu([X | xu] @ W1 + b1), K = 128 ----
            f32x4 acc[4];
            #pragma unroll
            for (int nt = 0; nt < 4; ++nt)
                acc[nt] = (f32x4){b1v[nt], b1v[nt], b1v[nt], b1v[nt]};
            #pragma unroll
            for (int nt = 0; nt < 4; ++nt)
                acc[nt] = __builtin_amdgcn_mfma_f32_16x16x32_bf16(a0,   w1f[0][nt], acc[nt], 0, 0, 0);
            #pragma unroll
            for (int nt = 0; nt < 4; ++nt)
                acc[nt] = __builtin_amdgcn_mfma_f32_16x16x32_bf16(a1,   w1f[1][nt], acc[nt], 0, 0, 0);
            #pragma unroll
            for (int nt = 0; nt < 4; ++nt)
                acc[nt] = __builtin_amdgcn_mfma_f32_16x16x32_bf16(axu0, w1f[2][nt], acc[nt], 0, 0, 0);
            #pragma unroll
            for (int nt = 0; nt < 4; ++nt)
                acc[nt] = __builtin_amdgcn_mfma_f32_16x16x32_bf16(axu1, w1f[3][nt], acc[nt], 0, 0, 0);

            // relu -> bf16 -> per-wave LDS transpose (C row=g*4+reg, col=nt*16+l15)
            #pragma unroll
            for (int nt = 0; nt < 4; ++nt)
                #pragma unroll
                for (int reg = 0; reg < 4; ++reg)
                    Hs[w][(g * 4 + reg) * 72 + nt * 16 + l15] =
                        (unsigned short)f2bf(fmaxf(acc[nt][reg], 0.f));

            // read back as A-fragments: row = l15, k-slice = ks2*32 + g*8
            bf16x8 h0 = *(const bf16x8*)&Hs[w][l15 * 72 +      g * 8];
            bf16x8 h1 = *(const bf16x8*)&Hs[w][l15 * 72 + 32 + g * 8];

            // ---- layer 2: H2 = relu(H1 @ W2 + b2) ----
            f32x4 acc2[4];
            #pragma unroll
            for (int nt = 0; nt < 4; ++nt)
                acc2[nt] = (f32x4){b2v[nt], b2v[nt], b2v[nt], b2v[nt]};
            #pragma unroll
            for (int nt = 0; nt < 4; ++nt)
                acc2[nt] = __builtin_amdgcn_mfma_f32_16x16x32_bf16(h0, w2f[0][nt], acc2[nt], 0, 0, 0);
            #pragma unroll
            for (int nt = 0; nt < 4; ++nt)
                acc2[nt] = __builtin_amdgcn_mfma_f32_16x16x32_bf16(h1, w2f[1][nt], acc2[nt], 0, 0, 0);

            // ---- layer 3: logit[l] = sum_n relu(H2[l][n]) * W3[n] ----
            float sv[4];
            #pragma unroll
            for (int reg = 0; reg < 4; ++reg) {
                float s = 0.f;
                #pragma unroll
                for (int nt = 0; nt < 4; ++nt)
                    s = fmaf(fmaxf(acc2[nt][reg], 0.f), w3v[nt], s);
                #pragma unroll
                for (int off = 1; off < 16; off <<= 1)
                    s += __shfl_xor(s, off);     // reduce over l15 (n within tile)
                sv[reg] = s;
            }
            if (l15 == 0) {
                float4 t = make_float4(sv[0], sv[1], sv[2], sv[3]);
                *(float4*)&Ls[w * 16 + g * 4] = t;   // rows l = w*16 + g*4 + reg
            }
        }
        __syncthreads();

        // ---- softmax over lanes (l = lane), computed redundantly per wave ----
        float lg = (lane < len) ? Ls[lane] : -INFINITY;
        float mx = lg;
        #pragma unroll
        for (int off = 1; off < 64; off <<= 1) mx = fmaxf(mx, __shfl_xor(mx, off));
        float e = __expf(lg - mx);               // 0 for masked lanes
        float ssum = e;
        #pragma unroll
        for (int off = 1; off < 64; off <<= 1) ssum += __shfl_xor(ssum, off);
        const float att = e / ssum;              // att[l] at lane l (0 beyond len)

        // ---- fp32 weighted sum over this wave's rows (re-gather, L2-hot) ----
        float po = 0.f;
        if (active) {
            #pragma unroll
            for (int rr = 0; rr < 16; ++rr) {
                float a   = __shfl(att, w * 16 + rr);   // 0 for rows >= len
                int   nb2 = __shfl(nbr, rr);            // lane rr holds row w*16+rr
                po = fmaf(a, i_table[nb2 * 64 + lane], po);
            }
        }
        Os[w][lane] = po;
        __syncthreads();
        if (w == 0)
            out[b * 64 + lane] = Os[0][lane] + Os[1][lane] + Os[2][lane] + Os[3][lane];
    }
}

extern "C" void kernel_launch(void* const* d_in, const int* in_sizes, int n_in,
                              void* d_out, int out_size, void* d_ws, size_t ws_size,
                              hipStream_t stream) {
    const float* u_table   = (const float*)d_in[0];
    const float* i_table   = (const float*)d_in[1];
    const float* W1        = (const float*)d_in[2];
    const float* b1        = (const float*)d_in[3];
    const float* W2        = (const float*)d_in[4];
    const float* b2        = (const float*)d_in[5];
    const float* W3        = (const float*)d_in[6];
    const float* b3        = (const float*)d_in[7];
    const int*   nodes     = (const int*)d_in[8];
    const int*   neighbors = (const int*)d_in[9];
    const int*   lengths   = (const int*)d_in[10];
    float* out = (float*)d_out;

    graphrec_mfma_kernel<<<dim3(NB / BPB), dim3(256), 0, stream>>>(
        u_table, i_table, W1, b1, W2, b2, W3, b3, nodes, neighbors, lengths, out);
}

// Round 3
// 25.824 us; speedup vs baseline: 5.3649x; 1.3604x over previous
//
#include <hip/hip_runtime.h>
#include <math.h>

#define NB    4096
#define LMAX  50
#define NWAVE 2048          // waves total; each handles 2 elements: wid, wid+2048

typedef short bf16x8 __attribute__((ext_vector_type(8)));
typedef float f32x4  __attribute__((ext_vector_type(4)));

// f32 -> bf16 (RNE) raw bits
__device__ __forceinline__ short f2bf(float f) {
    union { float f; unsigned u; } v; v.f = f;
    unsigned r = v.u + 0x7FFFu + ((v.u >> 16) & 1u);
    return (short)(r >> 16);
}
// bf16 raw bits -> f32 (exact)
__device__ __forceinline__ float bf2f(short s) {
    union { unsigned u; float f; } v; v.u = ((unsigned)(unsigned short)s) << 16;
    return v.f;
}
// load 8 consecutive f32 (32B-aligned) -> bf16x8 fragment
__device__ __forceinline__ bf16x8 cvt8(const float* __restrict__ p) {
    const float4* q = (const float4*)p;
    float4 x = q[0], y = q[1];
    bf16x8 r;
    r[0] = f2bf(x.x); r[1] = f2bf(x.y); r[2] = f2bf(x.z); r[3] = f2bf(x.w);
    r[4] = f2bf(y.x); r[5] = f2bf(y.y); r[6] = f2bf(y.z); r[7] = f2bf(y.w);
    return r;
}

// 4 waves/block, each wave fully independent after the weight-staging barrier.
__global__ __launch_bounds__(256) void graphrec_wave_kernel(
    const float* __restrict__ u_table,
    const float* __restrict__ i_table,
    const float* __restrict__ W1, const float* __restrict__ b1,
    const float* __restrict__ W2, const float* __restrict__ b2,
    const float* __restrict__ W3, const float* __restrict__ b3,
    const int* __restrict__ nodes,
    const int* __restrict__ neighbors,
    const int* __restrict__ lengths,
    float* __restrict__ out)
{
    // fragment-layout weights: frag f, lane -> 8 bf16 (one ds_read_b128 each)
    __shared__ __attribute__((aligned(16))) short WLDS[24][64][8];      // 24.5 KB
    // per-wave H1 transpose buffer (stride 72 shorts: measured conflict-free)
    __shared__ __attribute__((aligned(16))) unsigned short Hs[4][16 * 72]; // 9.2 KB
    __shared__ float Ls[4][16];                                          // e broadcast

    const int tid  = threadIdx.x;
    const int w    = tid >> 6;
    const int lane = tid & 63;
    const int l15  = lane & 15;
    const int g    = lane >> 4;

    // ---- cooperative build of fragment-layout weights (once per block) ----
    // B-frag: lane (l15,g) holds B[k][n], n = nt*16+l15, k = ks*32+g*8+i
    for (int f = w; f < 24; f += 4) {
        const float* Wsrc = (f < 16) ? W1 : W2;
        const int    fi   = (f < 16) ? f : f - 16;
        const int    ks   = fi >> 2, nt = fi & 3;
        bf16x8 fr;
        #pragma unroll
        for (int i = 0; i < 8; ++i)
            fr[i] = f2bf(Wsrc[(ks * 32 + g * 8 + i) * 64 + nt * 16 + l15]);
        *(bf16x8*)&WLDS[f][lane][0] = fr;
    }
    __syncthreads();

    bf16x8 w1f[4][4], w2f[2][4];
    #pragma unroll
    for (int ks = 0; ks < 4; ++ks)
        #pragma unroll
        for (int nt = 0; nt < 4; ++nt)
            w1f[ks][nt] = *(const bf16x8*)&WLDS[ks * 4 + nt][lane][0];
    #pragma unroll
    for (int ks = 0; ks < 2; ++ks)
        #pragma unroll
        for (int nt = 0; nt < 4; ++nt)
            w2f[ks][nt] = *(const bf16x8*)&WLDS[16 + ks * 4 + nt][lane][0];

    float b1v[4], b2v[4], w3v[4];
    #pragma unroll
    for (int nt = 0; nt < 4; ++nt) {
        b1v[nt] = b1[nt * 16 + l15];
        b2v[nt] = b2[nt * 16 + l15];
        w3v[nt] = W3[nt * 16 + l15];
    }
    // b3 is softmax-invariant; skip.

    const int wid = blockIdx.x * 4 + w;    // 0..2047

    for (int kk = 0; kk < 2; ++kk) {
        const int b    = wid + kk * NWAVE;
        const int len  = lengths[b];
        const int node = nodes[b];

        // node half of layer 1, once per element (rows identical):
        // hn[nt] = b1 + xu @ W1[64:128]
        bf16x8 axu0 = cvt8(u_table + node * 64 +      g * 8);
        bf16x8 axu1 = cvt8(u_table + node * 64 + 32 + g * 8);
        f32x4 hn[4];
        #pragma unroll
        for (int nt = 0; nt < 4; ++nt)
            hn[nt] = (f32x4){b1v[nt], b1v[nt], b1v[nt], b1v[nt]};
        #pragma unroll
        for (int nt = 0; nt < 4; ++nt)
            hn[nt] = __builtin_amdgcn_mfma_f32_16x16x32_bf16(axu0, w1f[2][nt], hn[nt], 0, 0, 0);
        #pragma unroll
        for (int nt = 0; nt < 4; ++nt)
            hn[nt] = __builtin_amdgcn_mfma_f32_16x16x32_bf16(axu1, w1f[3][nt], hn[nt], 0, 0, 0);

        float m = -INFINITY, ssum = 0.f;
        float accW[16];
        #pragma unroll
        for (int i = 0; i < 16; ++i) accW[i] = 0.f;

        const int ntile = (len + 15) >> 4;
        for (int t = 0; t < ntile; ++t) {
            const int  r  = t * 16 + l15;
            const bool vr = (r < len);
            bf16x8 a0 = {0,0,0,0,0,0,0,0}, a1 = {0,0,0,0,0,0,0,0};
            if (vr) {
                const int nbr = neighbors[b * LMAX + r];
                a0 = cvt8(i_table + nbr * 64 +      g * 8);
                a1 = cvt8(i_table + nbr * 64 + 32 + g * 8);
            }

            // ---- layer 1 (neighbor half), K=64 on top of hn ----
            f32x4 acc[4];
            #pragma unroll
            for (int nt = 0; nt < 4; ++nt) acc[nt] = hn[nt];
            #pragma unroll
            for (int nt = 0; nt < 4; ++nt)
                acc[nt] = __builtin_amdgcn_mfma_f32_16x16x32_bf16(a0, w1f[0][nt], acc[nt], 0, 0, 0);
            #pragma unroll
            for (int nt = 0; nt < 4; ++nt)
                acc[nt] = __builtin_amdgcn_mfma_f32_16x16x32_bf16(a1, w1f[1][nt], acc[nt], 0, 0, 0);

            // relu -> bf16 -> per-wave LDS transpose (C: row g*4+reg, col nt*16+l15)
            #pragma unroll
            for (int nt = 0; nt < 4; ++nt)
                #pragma unroll
                for (int reg = 0; reg < 4; ++reg)
                    Hs[w][(g * 4 + reg) * 72 + nt * 16 + l15] =
                        (unsigned short)f2bf(fmaxf(acc[nt][reg], 0.f));
            bf16x8 h0 = *(const bf16x8*)&Hs[w][l15 * 72 +      g * 8];
            bf16x8 h1 = *(const bf16x8*)&Hs[w][l15 * 72 + 32 + g * 8];

            // ---- layer 2 ----
            f32x4 c2[4];
            #pragma unroll
            for (int nt = 0; nt < 4; ++nt)
                c2[nt] = (f32x4){b2v[nt], b2v[nt], b2v[nt], b2v[nt]};
            #pragma unroll
            for (int nt = 0; nt < 4; ++nt)
                c2[nt] = __builtin_amdgcn_mfma_f32_16x16x32_bf16(h0, w2f[0][nt], c2[nt], 0, 0, 0);
            #pragma unroll
            for (int nt = 0; nt < 4; ++nt)
                c2[nt] = __builtin_amdgcn_mfma_f32_16x16x32_bf16(h1, w2f[1][nt], c2[nt], 0, 0, 0);

            // ---- layer 3 logits: row g*4+reg, reduce over n (l15 within group) ----
            float sv[4];
            #pragma unroll
            for (int reg = 0; reg < 4; ++reg) {
                float s = 0.f;
                #pragma unroll
                for (int nt = 0; nt < 4; ++nt)
                    s = fmaf(fmaxf(c2[nt][reg], 0.f), w3v[nt], s);
                #pragma unroll
                for (int off = 1; off < 16; off <<= 1) s += __shfl_xor(s, off);
                // mask invalid rows
                if (t * 16 + g * 4 + reg >= len) s = -INFINITY;
                sv[reg] = s;
            }

            // ---- online softmax (wave-uniform state) ----
            float tm = fmaxf(fmaxf(sv[0], sv[1]), fmaxf(sv[2], sv[3]));
            tm = fmaxf(tm, __shfl_xor(tm, 16));
            tm = fmaxf(tm, __shfl_xor(tm, 32));
            if (tm > m) {                       // wave-uniform branch
                const float nm = fmaxf(m, tm);
                const float sc = __expf(m - nm);   // first tile: exp(-inf)=0
                ssum *= sc;
                #pragma unroll
                for (int i = 0; i < 16; ++i) accW[i] *= sc;
                m = nm;
            }
            float e0 = __expf(sv[0] - m), e1 = __expf(sv[1] - m);
            float e2 = __expf(sv[2] - m), e3 = __expf(sv[3] - m);
            float es = (e0 + e1) + (e2 + e3);       // same across l15 in group
            es += __shfl_xor(es, 16);
            es += __shfl_xor(es, 32);
            ssum += es;

            // broadcast e to row owners via per-wave LDS
            if (l15 == 0) {
                float4 t4 = make_float4(e0, e1, e2, e3);
                *(float4*)&Ls[w][g * 4] = t4;       // rows g*4+reg
            }
            const float er = Ls[w][l15];            // e for row l15 (0 if invalid)

            // weighted-x partials straight from the A-fragments
            #pragma unroll
            for (int i = 0; i < 8; ++i) accW[i]     = fmaf(er, bf2f(a0[i]), accW[i]);
            #pragma unroll
            for (int i = 0; i < 8; ++i) accW[8 + i] = fmaf(er, bf2f(a1[i]), accW[8 + i]);
        }

        // ---- finalize: reduce over the 16 rows (l15), write 64 dims ----
        #pragma unroll
        for (int i = 0; i < 16; ++i) {
            #pragma unroll
            for (int off = 1; off < 16; off <<= 1)
                accW[i] += __shfl_xor(accW[i], off);
        }
        const float inv = 1.f / ssum;
        if (l15 == 0) {
            float4 o0 = make_float4(accW[0] * inv,  accW[1] * inv,  accW[2] * inv,  accW[3] * inv);
            float4 o1 = make_float4(accW[4] * inv,  accW[5] * inv,  accW[6] * inv,  accW[7] * inv);
            float4 o2 = make_float4(accW[8] * inv,  accW[9] * inv,  accW[10] * inv, accW[11] * inv);
            float4 o3 = make_float4(accW[12] * inv, accW[13] * inv, accW[14] * inv, accW[15] * inv);
            *(float4*)(out + b * 64 +      g * 8)     = o0;
            *(float4*)(out + b * 64 +      g * 8 + 4) = o1;
            *(float4*)(out + b * 64 + 32 + g * 8)     = o2;
            *(float4*)(out + b * 64 + 32 + g * 8 + 4) = o3;
        }
    }
}

extern "C" void kernel_launch(void* const* d_in, const int* in_sizes, int n_in,
                              void* d_out, int out_size, void* d_ws, size_t ws_size,
                              hipStream_t stream) {
    const float* u_table   = (const float*)d_in[0];
    const float* i_table   = (const float*)d_in[1];
    const float* W1        = (const float*)d_in[2];
    const float* b1        = (const float*)d_in[3];
    const float* W2        = (const float*)d_in[4];
    const float* b2        = (const float*)d_in[5];
    const float* W3        = (const float*)d_in[6];
    const float* b3        = (const float*)d_in[7];
    const int*   nodes     = (const int*)d_in[8];
    const int*   neighbors = (const int*)d_in[9];
    const int*   lengths   = (const int*)d_in[10];
    float* out = (float*)d_out;

    graphrec_wave_kernel<<<dim3(NWAVE / 4), dim3(256), 0, stream>>>(
        u_table, i_table, W1, b1, W2, b2, W3, b3, nodes, neighbors, lengths, out);
}